// Round 24
// baseline (220.778 us; speedup 1.0000x reference)
//
#include <hip/hip_runtime.h>

#define N_NODES 100000
#define N_EDGES 1000000
#define IN_DIM 32
#define HID_DIM 64
#define N2 (2 * N_NODES)          // (rel,node) buckets
#define NRANGE 8                  // dst ranges == XCD count
#define RNODES (N_NODES / NRANGE) // 12500
#define ECHUNK 2048               // edges per block-chunk in count/fill

typedef __attribute__((ext_vector_type(8))) short bf16x8;
typedef __attribute__((ext_vector_type(4))) float f32x4;
typedef __attribute__((ext_vector_type(4))) int int32x4;   // nt-load-compatible
#define MFMA16x32 __builtin_amdgcn_mfma_f32_16x16x32_bf16

// ============ helpers ============

__device__ __forceinline__ unsigned short f2bf(float f) {
    unsigned u = __float_as_uint(f);
    return (unsigned short)((u + 0x7FFFu + ((u >> 16) & 1u)) >> 16);  // RNE
}

#define MACC4(A, v, m)                \
    A.x = fmaf((v).x, m, A.x);        \
    A.y = fmaf((v).y, m, A.y);        \
    A.z = fmaf((v).z, m, A.z);        \
    A.w = fmaf((v).w, m, A.w);

#define BUNPACK(v_, u) {                           \
    v_.x = __uint_as_float((u).x << 16);           \
    v_.y = __uint_as_float((u).x & 0xFFFF0000u);   \
    v_.z = __uint_as_float((u).y << 16);           \
    v_.w = __uint_as_float((u).y & 0xFFFF0000u);   \
}

#define BMACC4(A, u, m) { float4 v_; BUNPACK(v_, u) MACC4(A, v_, m) }

// ============ merged prep: rd + deg-zero + xb pack + weight pack ============

__global__ __launch_bounds__(256) void k_prep(
    const int* __restrict__ ei, const int* __restrict__ ea,
    const float* __restrict__ x,
    const float* __restrict__ root1, const float* __restrict__ W1,
    const float* __restrict__ root2, const float* __restrict__ W2,
    int* __restrict__ rd, int* __restrict__ deg,
    unsigned short* __restrict__ xb,
    unsigned short* __restrict__ wb1, unsigned short* __restrict__ wb2)
{
    int i = blockIdx.x * 256 + threadIdx.x;
    if (i < N2) deg[i] = 0;
    if (i < N_EDGES) rd[i] = (ei[N_EDGES + i] << 1) | ea[2 * i + 1];
    if (i < N_NODES * IN_DIM / 4) {
        float4 v = ((const float4*)x)[i];
        ushort4 o;
        o.x = f2bf(v.x); o.y = f2bf(v.y); o.z = f2bf(v.z); o.w = f2bf(v.w);
        ((ushort4*)xb)[i] = o;
    }
    if (i < 6144) {
        int e = i & 7, lane = (i >> 3) & 63, fid = i >> 9;
        int jt = fid & 3, mat = fid >> 2;
        int k = (lane >> 4) * 8 + e;
        int j = jt * 16 + (lane & 15);
        float v = (mat == 0) ? root1[k * 64 + j]
                             : W1[(mat - 1) * (IN_DIM * HID_DIM) + k * 64 + j];
        wb1[i] = f2bf(v);
    } else if (i < 6144 + 12288) {
        int i2 = i - 6144;
        int e = i2 & 7, lane = (i2 >> 3) & 63, fid = i2 >> 9;
        int jt = fid & 3, ks = (fid >> 2) & 1, mat = fid >> 3;
        int k = ks * 32 + (lane >> 4) * 8 + e;
        int j = jt * 16 + (lane & 15);
        float v = (mat == 0) ? root2[k * 64 + j]
                             : W2[(mat - 1) * (HID_DIM * HID_DIM) + k * 64 + j];
        wb2[i2] = f2bf(v);
    }
}

// ============ CSR build: XCD-local histogram -> scan -> XCD-local fill ============
// r23: nt-LOADS were null (WRITE unchanged) -> amplification is write-allocate
// on the scattered 4B elist STORES (allocate -> dirty-evict -> REFETCH, the
// 37MB FETCH). r24: nontemporal STORES for elist (no-retention/write-through).

__global__ __launch_bounds__(256) void k_count(
    const int* __restrict__ rd, int* __restrict__ deg)
{
    int range = blockIdx.x & (NRANGE - 1);
    int chunk = blockIdx.x >> 3;
    int lo = range * RNODES;
    int e0 = chunk * ECHUNK;
    int e1 = min(e0 + ECHUNK, N_EDGES);
    for (int e = e0 + threadIdx.x * 4; e < e1; e += 1024) {
        int32x4 v4 = __builtin_nontemporal_load((const int32x4*)(rd + e));
#define CNT1(vv)                                                      \
        {                                                             \
            int dst = (vv) >> 1;                                      \
            if ((unsigned)(dst - lo) < (unsigned)RNODES)              \
                atomicAdd(&deg[((vv) & 1) * N_NODES + dst], 1);       \
        }
        CNT1(v4.x) CNT1(v4.y) CNT1(v4.z) CNT1(v4.w)
#undef CNT1
    }
}

__global__ __launch_bounds__(256) void k_scan_local(
    const int* __restrict__ deg, int* __restrict__ offs, int* __restrict__ bsum)
{
    int t = threadIdx.x;
    int i = blockIdx.x * 256 + t;
    int v = (i < N2) ? deg[i] : 0;
    int lane = t & 63, w = t >> 6;
    int s = v;
#pragma unroll
    for (int off = 1; off < 64; off <<= 1) {
        int u = __shfl_up(s, off);
        if (lane >= off) s += u;
    }
    __shared__ int wsum[4];
    if (lane == 63) wsum[w] = s;
    __syncthreads();
    int add = 0;
    for (int ww = 0; ww < w; ++ww) add += wsum[ww];
    s += add;
    if (i < N2) offs[i] = s - v;
    if (t == 255) bsum[blockIdx.x] = s;
}

__global__ __launch_bounds__(64) void k_scan_blocks(int* __restrict__ bsum, int nblk)
{
    int lane = threadIdx.x;  // single wave
    int carry = 0;
    for (int base = 0; base < nblk; base += 64) {
        int i = base + lane;
        int v = (i < nblk) ? bsum[i] : 0;
        int s = v;
#pragma unroll
        for (int off = 1; off < 64; off <<= 1) {
            int u = __shfl_up(s, off);
            if (lane >= off) s += u;
        }
        if (i < nblk) bsum[i] = carry + s - v;
        carry += __shfl(s, 63);
    }
}

__global__ __launch_bounds__(256) void k_scan_add(
    const int* __restrict__ offs, const int* __restrict__ bsum,
    const int* __restrict__ deg,
    int* __restrict__ cursor, int2* __restrict__ od)
{
    int i = blockIdx.x * 256 + threadIdx.x;
    if (i >= N2) return;
    int o = offs[i] + bsum[i >> 8];
    cursor[i] = o;
    od[i] = make_int2(o, deg[i]);
}

__global__ __launch_bounds__(256) void k_fill(
    const int* __restrict__ rd, const int* __restrict__ ei,
    int* __restrict__ cursor, int* __restrict__ elist)
{
    int range = blockIdx.x & (NRANGE - 1);
    int chunk = blockIdx.x >> 3;
    int lo = range * RNODES;
    int e0 = chunk * ECHUNK;
    int e1 = min(e0 + ECHUNK, N_EDGES);
    for (int e = e0 + threadIdx.x * 4; e < e1; e += 1024) {
        int32x4 v4 = __builtin_nontemporal_load((const int32x4*)(rd + e));
#define FIL1(vv, i)                                                   \
        {                                                             \
            int dst = (vv) >> 1;                                      \
            if ((unsigned)(dst - lo) < (unsigned)RNODES) {            \
                int src = __builtin_nontemporal_load(ei + e + i);     \
                int pos = atomicAdd(&cursor[((vv) & 1) * N_NODES + dst], 1); \
                __builtin_nontemporal_store(src, elist + pos);        \
            }                                                         \
        }
        FIL1(v4.x, 0) FIL1(v4.y, 1) FIL1(v4.z, 2) FIL1(v4.w, 3)
#undef FIL1
    }
}

// ============ MFMA GEMM kernels (r20 structure, verified) ============

__global__ __launch_bounds__(512, 8) void k_mgemm1(
    const unsigned short* __restrict__ xb,   // [N][32] bf16
    const unsigned short* __restrict__ wb1,  // 12 B-frags
    const float* __restrict__ b1,
    unsigned short* __restrict__ Rb,         // [N][64] bf16: x@root1 + b1
    unsigned short* __restrict__ Y)          // [2][N][64] bf16
{
    int tid = threadIdx.x;
    int lane = tid & 63;
    int wv   = tid >> 6;
    int n0   = blockIdx.x * 128 + wv * 16;

    int srcn = min(n0 + (lane & 15), N_NODES - 1);
    bf16x8 a = *(const bf16x8*)(xb + (size_t)srcn * IN_DIM + (lane >> 4) * 8);

    f32x4 z = {0.f, 0.f, 0.f, 0.f};
    f32x4 cR0 = z, cR1 = z, cR2 = z, cR3 = z;
    f32x4 c00 = z, c01 = z, c02 = z, c03 = z;
    f32x4 c10 = z, c11 = z, c12 = z, c13 = z;

#define B1FRAG(mat, jt) (*(const bf16x8*)(wb1 + ((mat) * 4 + (jt)) * 512 + lane * 8))
    cR0 = MFMA16x32(a, B1FRAG(0, 0), cR0, 0, 0, 0);
    cR1 = MFMA16x32(a, B1FRAG(0, 1), cR1, 0, 0, 0);
    cR2 = MFMA16x32(a, B1FRAG(0, 2), cR2, 0, 0, 0);
    cR3 = MFMA16x32(a, B1FRAG(0, 3), cR3, 0, 0, 0);
    c00 = MFMA16x32(a, B1FRAG(1, 0), c00, 0, 0, 0);
    c01 = MFMA16x32(a, B1FRAG(1, 1), c01, 0, 0, 0);
    c02 = MFMA16x32(a, B1FRAG(1, 2), c02, 0, 0, 0);
    c03 = MFMA16x32(a, B1FRAG(1, 3), c03, 0, 0, 0);
    c10 = MFMA16x32(a, B1FRAG(2, 0), c10, 0, 0, 0);
    c11 = MFMA16x32(a, B1FRAG(2, 1), c11, 0, 0, 0);
    c12 = MFMA16x32(a, B1FRAG(2, 2), c12, 0, 0, 0);
    c13 = MFMA16x32(a, B1FRAG(2, 3), c13, 0, 0, 0);
#undef B1FRAG

    if (n0 >= N_NODES) return;   // N%16==0 -> whole wave valid or invalid
    unsigned short* Y0 = Y;
    unsigned short* Y1 = Y + (size_t)N_NODES * HID_DIM;
    int col   = lane & 15;
    int rbase = n0 + (lane >> 4) * 4;

#define OUT1(cR, cA, cB, jt)                                          \
    {                                                                 \
        int j = (jt) * 16 + col;                                      \
        float bj = b1[j];                                             \
        _Pragma("unroll")                                             \
        for (int r = 0; r < 4; ++r) {                                 \
            size_t node = (size_t)(rbase + r);                        \
            Rb[node * HID_DIM + j] = f2bf(cR[r] + bj);                \
            Y0[node * HID_DIM + j] = f2bf(cA[r]);                     \
            Y1[node * HID_DIM + j] = f2bf(cB[r]);                     \
        }                                                             \
    }
    OUT1(cR0, c00, c10, 0)
    OUT1(cR1, c01, c11, 1)
    OUT1(cR2, c02, c12, 2)
    OUT1(cR3, c03, c13, 3)
#undef OUT1
}

__global__ __launch_bounds__(512, 8) void k_mgemm2(
    const unsigned short* __restrict__ h1b,  // [N][64] bf16
    const unsigned short* __restrict__ wb2,  // 24 B-frags
    const float* __restrict__ b2,
    unsigned short* __restrict__ Rb,         // [N][64] bf16: h1@root2 + b2
    unsigned short* __restrict__ Y)          // [2][N][64] bf16
{
    int tid = threadIdx.x;
    int lane = tid & 63;
    int wv   = tid >> 6;
    int n0   = blockIdx.x * 128 + wv * 16;

    int srcn = min(n0 + (lane & 15), N_NODES - 1);
    const unsigned short* pa = h1b + (size_t)srcn * HID_DIM + (lane >> 4) * 8;
    bf16x8 a0 = *(const bf16x8*)(pa);        // k 0..31
    bf16x8 a1 = *(const bf16x8*)(pa + 32);   // k 32..63

    f32x4 z = {0.f, 0.f, 0.f, 0.f};
    f32x4 cR0 = z, cR1 = z, cR2 = z, cR3 = z;
    f32x4 c00 = z, c01 = z, c02 = z, c03 = z;
    f32x4 c10 = z, c11 = z, c12 = z, c13 = z;

#define B2FRAG(mat, ks, jt) \
    (*(const bf16x8*)(wb2 + (((mat) * 2 + (ks)) * 4 + (jt)) * 512 + lane * 8))
#define DO2(cv, mat, jt)                                     \
    cv = MFMA16x32(a0, B2FRAG(mat, 0, jt), cv, 0, 0, 0);     \
    cv = MFMA16x32(a1, B2FRAG(mat, 1, jt), cv, 0, 0, 0);
    DO2(cR0, 0, 0) DO2(cR1, 0, 1) DO2(cR2, 0, 2) DO2(cR3, 0, 3)
    DO2(c00, 1, 0) DO2(c01, 1, 1) DO2(c02, 1, 2) DO2(c03, 1, 3)
    DO2(c10, 2, 0) DO2(c11, 2, 1) DO2(c12, 2, 2) DO2(c13, 2, 3)
#undef DO2
#undef B2FRAG

    if (n0 >= N_NODES) return;
    unsigned short* Y0 = Y;
    unsigned short* Y1 = Y + (size_t)N_NODES * HID_DIM;
    int col   = lane & 15;
    int rbase = n0 + (lane >> 4) * 4;

#define OUT2(cR, cA, cB, jt)                                          \
    {                                                                 \
        int j = (jt) * 16 + col;                                      \
        float bj = b2[j];                                             \
        _Pragma("unroll")                                             \
        for (int r = 0; r < 4; ++r) {                                 \
            size_t node = (size_t)(rbase + r);                        \
            Rb[node * HID_DIM + j] = f2bf(cR[r] + bj);                \
            Y0[node * HID_DIM + j] = f2bf(cA[r]);                     \
            Y1[node * HID_DIM + j] = f2bf(cB[r]);                     \
        }                                                             \
    }
    OUT2(cR0, c00, c10, 0)
    OUT2(cR1, c01, c11, 1)
    OUT2(cR2, c02, c12, 2)
    OUT2(cR3, c03, c13, 3)
#undef OUT2
}

// ============ gather-sum kernels (r17 structure, Rb bf16) ============

__global__ __launch_bounds__(512, 8) void k_gather1(
    const unsigned short* __restrict__ Y,   // [2][N][64] bf16
    const unsigned short* __restrict__ Rb,  // [N][64] bf16 (incl. b1)
    const int2* __restrict__ od,
    const int* __restrict__ elist,
    unsigned short* __restrict__ h1b)       // [N][64] bf16
{
    int tid = threadIdx.x;
    int lane = tid & 63;
    int wv   = __builtin_amdgcn_readfirstlane(tid >> 6);
    int n0   = __builtin_amdgcn_readfirstlane(blockIdx.x * 32 + wv * 4);

    int sub  = lane >> 4;
    int node = n0 + sub;
    int q    = lane & 15;
    int base = lane & 48;

    const unsigned short* Y0 = Y;
    const unsigned short* Y1 = Y + (size_t)N_NODES * HID_DIM;

    int2 o0 = od[node];
    int2 o1 = od[N_NODES + node];
    int d0 = o0.y, d1 = o1.y;
    int er0 = (q < d0) ? elist[o0.x + q] : 0;
    int er1 = (q < d1) ? elist[o1.x + q] : 0;

    int dm = max(d0, d1);
    dm = max(dm, __shfl_xor(dm, 16));
    dm = max(dm, __shfl_xor(dm, 32));
    int kend = min(dm, 16);

    float4 A0 = make_float4(0.f, 0.f, 0.f, 0.f);
    float4 A1 = make_float4(0.f, 0.f, 0.f, 0.f);
    for (int k = 0; k < kend; ++k) {
        int i0 = __shfl(er0, base + k);
        int i1 = __shfl(er1, base + k);
        uint2 u0 = *(const uint2*)(Y0 + (size_t)i0 * HID_DIM + q * 4);
        uint2 u1 = *(const uint2*)(Y1 + (size_t)i1 * HID_DIM + q * 4);
        float m0 = (k < d0) ? 1.0f : 0.0f;
        float m1 = (k < d1) ? 1.0f : 0.0f;
        BMACC4(A0, u0, m0)
        BMACC4(A1, u1, m1)
    }
    if (dm > 16) {
        for (int k = 16; k < dm; ++k) {
            int i0 = 0, i1 = 0;
            if (k < d0) i0 = elist[o0.x + k];
            if (k < d1) i1 = elist[o1.x + k];
            uint2 u0 = *(const uint2*)(Y0 + (size_t)i0 * HID_DIM + q * 4);
            uint2 u1 = *(const uint2*)(Y1 + (size_t)i1 * HID_DIM + q * 4);
            float m0 = (k < d0) ? 1.0f : 0.0f;
            float m1 = (k < d1) ? 1.0f : 0.0f;
            BMACC4(A0, u0, m0)
            BMACC4(A1, u1, m1)
        }
    }
    float i0v = 1.0f / fmaxf((float)d0, 1.0f);
    float i1v = 1.0f / fmaxf((float)d1, 1.0f);
    uint2 ru = *(const uint2*)(Rb + (size_t)node * HID_DIM + q * 4);
    float4 Rq; BUNPACK(Rq, ru)
    ushort4 o;
    o.x = f2bf(fmaxf(Rq.x + A0.x * i0v + A1.x * i1v, 0.0f));
    o.y = f2bf(fmaxf(Rq.y + A0.y * i0v + A1.y * i1v, 0.0f));
    o.z = f2bf(fmaxf(Rq.z + A0.z * i0v + A1.z * i1v, 0.0f));
    o.w = f2bf(fmaxf(Rq.w + A0.w * i0v + A1.w * i1v, 0.0f));
    *(ushort4*)(h1b + (size_t)node * HID_DIM + q * 4) = o;
}

__global__ __launch_bounds__(512, 8) void k_gather2(
    const unsigned short* __restrict__ Y,   // [2][N][64] bf16
    const unsigned short* __restrict__ Rb,  // [N][64] bf16 (incl. b2)
    const int2* __restrict__ od,
    const int* __restrict__ elist,
    const float* __restrict__ Wc,           // [64][2]
    const float* __restrict__ bc,           // [2]
    float* __restrict__ out)                // [N][2]
{
    int tid = threadIdx.x;
    int lane = tid & 63;
    int wv   = __builtin_amdgcn_readfirstlane(tid >> 6);
    int n0   = __builtin_amdgcn_readfirstlane(blockIdx.x * 32 + wv * 4);

    int sub  = lane >> 4;
    int node = n0 + sub;
    int q    = lane & 15;
    int base = lane & 48;

    const unsigned short* Y0 = Y;
    const unsigned short* Y1 = Y + (size_t)N_NODES * HID_DIM;

    int2 o0 = od[node];
    int2 o1 = od[N_NODES + node];
    int d0 = o0.y, d1 = o1.y;
    int er0 = (q < d0) ? elist[o0.x + q] : 0;
    int er1 = (q < d1) ? elist[o1.x + q] : 0;

    int dm = max(d0, d1);
    dm = max(dm, __shfl_xor(dm, 16));
    dm = max(dm, __shfl_xor(dm, 32));
    int kend = min(dm, 16);

    float4 A0 = make_float4(0.f, 0.f, 0.f, 0.f);
    float4 A1 = make_float4(0.f, 0.f, 0.f, 0.f);
    for (int k = 0; k < kend; ++k) {
        int i0 = __shfl(er0, base + k);
        int i1 = __shfl(er1, base + k);
        uint2 u0 = *(const uint2*)(Y0 + (size_t)i0 * HID_DIM + q * 4);
        uint2 u1 = *(const uint2*)(Y1 + (size_t)i1 * HID_DIM + q * 4);
        float m0 = (k < d0) ? 1.0f : 0.0f;
        float m1 = (k < d1) ? 1.0f : 0.0f;
        BMACC4(A0, u0, m0)
        BMACC4(A1, u1, m1)
    }
    if (dm > 16) {
        for (int k = 16; k < dm; ++k) {
            int i0 = 0, i1 = 0;
            if (k < d0) i0 = elist[o0.x + k];
            if (k < d1) i1 = elist[o1.x + k];
            uint2 u0 = *(const uint2*)(Y0 + (size_t)i0 * HID_DIM + q * 4);
            uint2 u1 = *(const uint2*)(Y1 + (size_t)i1 * HID_DIM + q * 4);
            float m0 = (k < d0) ? 1.0f : 0.0f;
            float m1 = (k < d1) ? 1.0f : 0.0f;
            BMACC4(A0, u0, m0)
            BMACC4(A1, u1, m1)
        }
    }
    float i0v = 1.0f / fmaxf((float)d0, 1.0f);
    float i1v = 1.0f / fmaxf((float)d1, 1.0f);
    uint2 ru = *(const uint2*)(Rb + (size_t)node * HID_DIM + q * 4);
    float4 Rq; BUNPACK(Rq, ru)
    float4 h2;
    h2.x = fmaxf(Rq.x + A0.x * i0v + A1.x * i1v, 0.0f);
    h2.y = fmaxf(Rq.y + A0.y * i0v + A1.y * i1v, 0.0f);
    h2.z = fmaxf(Rq.z + A0.z * i0v + A1.z * i1v, 0.0f);
    h2.w = fmaxf(Rq.w + A0.w * i0v + A1.w * i1v, 0.0f);

    float4 wcA = *(const float4*)(Wc + 8 * q);
    float4 wcB = *(const float4*)(Wc + 8 * q + 4);
    float v0 = h2.x * wcA.x + h2.y * wcA.z + h2.z * wcB.x + h2.w * wcB.z;
    float v1 = h2.x * wcA.y + h2.y * wcA.w + h2.z * wcB.y + h2.w * wcB.w;
#pragma unroll
    for (int off = 1; off <= 8; off <<= 1) {
        v0 += __shfl_xor(v0, off);
        v1 += __shfl_xor(v1, off);
    }
    if (q == 0) {
        out[(size_t)node * 2 + 0] = v0 + bc[0];
        out[(size_t)node * 2 + 1] = v1 + bc[1];
    }
}

// ============ launch ============

extern "C" void kernel_launch(void* const* d_in, const int* in_sizes, int n_in,
                              void* d_out, int out_size, void* d_ws, size_t ws_size,
                              hipStream_t stream) {
    const float* x     = (const float*)d_in[0];
    const int*   ei    = (const int*)d_in[1];
    const int*   ea    = (const int*)d_in[2];
    const float* W1    = (const float*)d_in[3];
    const float* root1 = (const float*)d_in[4];
    const float* b1    = (const float*)d_in[5];
    const float* W2    = (const float*)d_in[6];
    const float* root2 = (const float*)d_in[7];
    const float* b2    = (const float*)d_in[8];
    const float* Wc    = (const float*)d_in[9];
    const float* bc    = (const float*)d_in[10];
    float* out = (float*)d_out;

    // ws layout (bytes), peak ~69.6 MB (proven budget >= 77.6 MB):
    //   deg    @ 0        : 2N int   (800000)
    //   offs   @ 800000   : 2N int   (800000)
    //   od     @ 1600000  : 2N int2  (1600000)
    //   elist  @ 3200000  : E int    (4000000)
    //   cursor @ 7200000  : 2N int   (800000)
    //   bsum   @ 8000000  : 4096
    //   rd     @ 8004096  : E int    (4000000)
    //   Y      @ 12004096 : 2N*64 bf16 (25600000)
    //   Rb     @ 37604096 : N*64 bf16  (12800000)
    //   h1b    @ 50404096 : N*64 bf16  (12800000)
    //   xb     @ 63204096 : N*32 bf16  (6400000)
    //   wb1    @ 69604096 : 6144 bf16  (12288)
    //   wb2    @ 69616384 : 12288 bf16 (24576)
    char* ws = (char*)d_ws;
    int*   deg    = (int*)(ws);
    int*   offs   = (int*)(ws + 800000);
    int2*  od     = (int2*)(ws + 1600000);
    int*   elist  = (int*)(ws + 3200000);
    int*   cursor = (int*)(ws + 7200000);
    int*   bsum   = (int*)(ws + 8000000);
    int*   rd     = (int*)(ws + 8004096);
    unsigned short* Y   = (unsigned short*)(ws + 12004096);
    unsigned short* Rb  = (unsigned short*)(ws + 37604096);
    unsigned short* h1b = (unsigned short*)(ws + 50404096);
    unsigned short* xb  = (unsigned short*)(ws + 63204096);
    unsigned short* wb1 = (unsigned short*)(ws + 69604096);
    unsigned short* wb2 = (unsigned short*)(ws + 69616384);

    const int nblk_scan = (N2 + 255) / 256;                            // 782
    const int grid_e    = (N_EDGES + 255) / 256;                       // 3907
    const int grid_cf   = ((N_EDGES + ECHUNK - 1) / ECHUNK) * NRANGE;  // 489*8
    const int grid_m    = (N_NODES + 127) / 128;                       // 782 (mfma gemms)
    const int grid_n    = N_NODES / 32;                                // 3125 (gathers)

    k_prep<<<grid_e, 256, 0, stream>>>(ei, ea, x, root1, W1, root2, W2,
                                       rd, deg, xb, wb1, wb2);
    k_count<<<grid_cf, 256, 0, stream>>>(rd, deg);
    k_scan_local<<<nblk_scan, 256, 0, stream>>>(deg, offs, bsum);
    k_scan_blocks<<<1, 64, 0, stream>>>(bsum, nblk_scan);
    k_scan_add<<<nblk_scan, 256, 0, stream>>>(offs, bsum, deg, cursor, od);
    k_fill<<<grid_cf, 256, 0, stream>>>(rd, ei, cursor, elist);

    // layer 1: MFMA transform, then gather (linearity: mean(x)@W == mean(x@W))
    k_mgemm1<<<grid_m, 512, 0, stream>>>(xb, wb1, b1, Rb, Y);
    k_gather1<<<grid_n, 512, 0, stream>>>(Y, Rb, od, elist, h1b);

    // layer 2 + classifier
    k_mgemm2<<<grid_m, 512, 0, stream>>>(h1b, wb2, b2, Rb, Y);
    k_gather2<<<grid_n, 512, 0, stream>>>(Y, Rb, od, elist, Wc, bc, out);
}

// Round 25
// 207.656 us; speedup vs baseline: 1.0632x; 1.0632x over previous
//
#include <hip/hip_runtime.h>

#define N_NODES 100000
#define N_EDGES 1000000
#define IN_DIM 32
#define HID_DIM 64
#define N2 (2 * N_NODES)          // (rel,node) buckets
#define NRANGE 8                  // dst ranges == XCD count
#define RNODES (N_NODES / NRANGE) // 12500
#define ECHUNK 2048               // edges per block-chunk in count/fill

typedef __attribute__((ext_vector_type(8))) short bf16x8;
typedef __attribute__((ext_vector_type(4))) float f32x4;
#define MFMA16x32 __builtin_amdgcn_mfma_f32_16x16x32_bf16

// ============ helpers ============

__device__ __forceinline__ unsigned short f2bf(float f) {
    unsigned u = __float_as_uint(f);
    return (unsigned short)((u + 0x7FFFu + ((u >> 16) & 1u)) >> 16);  // RNE
}

#define MACC4(A, v, m)                \
    A.x = fmaf((v).x, m, A.x);        \
    A.y = fmaf((v).y, m, A.y);        \
    A.z = fmaf((v).z, m, A.z);        \
    A.w = fmaf((v).w, m, A.w);

#define BUNPACK(v_, u) {                           \
    v_.x = __uint_as_float((u).x << 16);           \
    v_.y = __uint_as_float((u).x & 0xFFFF0000u);   \
    v_.z = __uint_as_float((u).y << 16);           \
    v_.w = __uint_as_float((u).y & 0xFFFF0000u);   \
}

#define BMACC4(A, u, m) { float4 v_; BUNPACK(v_, u) MACC4(A, v_, m) }

// ============ merged prep: rd + deg-zero + xb pack + weight pack ============

__global__ __launch_bounds__(256) void k_prep(
    const int* __restrict__ ei, const int* __restrict__ ea,
    const float* __restrict__ x,
    const float* __restrict__ root1, const float* __restrict__ W1,
    const float* __restrict__ root2, const float* __restrict__ W2,
    int* __restrict__ rd, int* __restrict__ deg,
    unsigned short* __restrict__ xb,
    unsigned short* __restrict__ wb1, unsigned short* __restrict__ wb2)
{
    int i = blockIdx.x * 256 + threadIdx.x;
    if (i < N2) deg[i] = 0;
    if (i < N_EDGES) rd[i] = (ei[N_EDGES + i] << 1) | ea[2 * i + 1];
    if (i < N_NODES * IN_DIM / 4) {
        float4 v = ((const float4*)x)[i];
        ushort4 o;
        o.x = f2bf(v.x); o.y = f2bf(v.y); o.z = f2bf(v.z); o.w = f2bf(v.w);
        ((ushort4*)xb)[i] = o;
    }
    if (i < 6144) {
        int e = i & 7, lane = (i >> 3) & 63, fid = i >> 9;
        int jt = fid & 3, mat = fid >> 2;
        int k = (lane >> 4) * 8 + e;
        int j = jt * 16 + (lane & 15);
        float v = (mat == 0) ? root1[k * 64 + j]
                             : W1[(mat - 1) * (IN_DIM * HID_DIM) + k * 64 + j];
        wb1[i] = f2bf(v);
    } else if (i < 6144 + 12288) {
        int i2 = i - 6144;
        int e = i2 & 7, lane = (i2 >> 3) & 63, fid = i2 >> 9;
        int jt = fid & 3, ks = (fid >> 2) & 1, mat = fid >> 3;
        int k = ks * 32 + (lane >> 4) * 8 + e;
        int j = jt * 16 + (lane & 15);
        float v = (mat == 0) ? root2[k * 64 + j]
                             : W2[(mat - 1) * (HID_DIM * HID_DIM) + k * 64 + j];
        wb2[i2] = f2bf(v);
    }
}

// ============ CSR build: XCD-local histogram -> scan -> XCD-local fill ============
// r23/r24 lessons [HW]: nt-loads cost ~5us (44->49), nt-stores cost 2.7x WRITE
// (38->102MB: each 4B scatter becomes its own partial-line HBM transaction).
// PLAIN int4 loads + plain stores are the measured best; the ~8x write
// amplification of random 4B scatters is inherent to this memory system.

__global__ __launch_bounds__(256) void k_count(
    const int* __restrict__ rd, int* __restrict__ deg)
{
    int range = blockIdx.x & (NRANGE - 1);
    int chunk = blockIdx.x >> 3;
    int lo = range * RNODES;
    int e0 = chunk * ECHUNK;
    int e1 = min(e0 + ECHUNK, N_EDGES);
    for (int e = e0 + threadIdx.x * 4; e < e1; e += 1024) {
        int4 v4 = *(const int4*)(rd + e);
#define CNT1(vv)                                                      \
        {                                                             \
            int dst = (vv) >> 1;                                      \
            if ((unsigned)(dst - lo) < (unsigned)RNODES)              \
                atomicAdd(&deg[((vv) & 1) * N_NODES + dst], 1);       \
        }
        CNT1(v4.x) CNT1(v4.y) CNT1(v4.z) CNT1(v4.w)
#undef CNT1
    }
}

__global__ __launch_bounds__(256) void k_scan_local(
    const int* __restrict__ deg, int* __restrict__ offs, int* __restrict__ bsum)
{
    int t = threadIdx.x;
    int i = blockIdx.x * 256 + t;
    int v = (i < N2) ? deg[i] : 0;
    int lane = t & 63, w = t >> 6;
    int s = v;
#pragma unroll
    for (int off = 1; off < 64; off <<= 1) {
        int u = __shfl_up(s, off);
        if (lane >= off) s += u;
    }
    __shared__ int wsum[4];
    if (lane == 63) wsum[w] = s;
    __syncthreads();
    int add = 0;
    for (int ww = 0; ww < w; ++ww) add += wsum[ww];
    s += add;
    if (i < N2) offs[i] = s - v;
    if (t == 255) bsum[blockIdx.x] = s;
}

__global__ __launch_bounds__(64) void k_scan_blocks(int* __restrict__ bsum, int nblk)
{
    int lane = threadIdx.x;  // single wave
    int carry = 0;
    for (int base = 0; base < nblk; base += 64) {
        int i = base + lane;
        int v = (i < nblk) ? bsum[i] : 0;
        int s = v;
#pragma unroll
        for (int off = 1; off < 64; off <<= 1) {
            int u = __shfl_up(s, off);
            if (lane >= off) s += u;
        }
        if (i < nblk) bsum[i] = carry + s - v;
        carry += __shfl(s, 63);
    }
}

__global__ __launch_bounds__(256) void k_scan_add(
    const int* __restrict__ offs, const int* __restrict__ bsum,
    const int* __restrict__ deg,
    int* __restrict__ cursor, int2* __restrict__ od)
{
    int i = blockIdx.x * 256 + threadIdx.x;
    if (i >= N2) return;
    int o = offs[i] + bsum[i >> 8];
    cursor[i] = o;
    od[i] = make_int2(o, deg[i]);
}

__global__ __launch_bounds__(256) void k_fill(
    const int* __restrict__ rd, const int* __restrict__ ei,
    int* __restrict__ cursor, int* __restrict__ elist)
{
    int range = blockIdx.x & (NRANGE - 1);
    int chunk = blockIdx.x >> 3;
    int lo = range * RNODES;
    int e0 = chunk * ECHUNK;
    int e1 = min(e0 + ECHUNK, N_EDGES);
    for (int e = e0 + threadIdx.x * 4; e < e1; e += 1024) {
        int4 v4 = *(const int4*)(rd + e);
#define FIL1(vv, i)                                                   \
        {                                                             \
            int dst = (vv) >> 1;                                      \
            if ((unsigned)(dst - lo) < (unsigned)RNODES) {            \
                int src = ei[e + i];                                  \
                int pos = atomicAdd(&cursor[((vv) & 1) * N_NODES + dst], 1); \
                elist[pos] = src;                                     \
            }                                                         \
        }
        FIL1(v4.x, 0) FIL1(v4.y, 1) FIL1(v4.z, 2) FIL1(v4.w, 3)
#undef FIL1
    }
}

// ============ MFMA GEMM kernels (r20 structure, verified) ============

__global__ __launch_bounds__(512, 8) void k_mgemm1(
    const unsigned short* __restrict__ xb,   // [N][32] bf16
    const unsigned short* __restrict__ wb1,  // 12 B-frags
    const float* __restrict__ b1,
    unsigned short* __restrict__ Rb,         // [N][64] bf16: x@root1 + b1
    unsigned short* __restrict__ Y)          // [2][N][64] bf16
{
    int tid = threadIdx.x;
    int lane = tid & 63;
    int wv   = tid >> 6;
    int n0   = blockIdx.x * 128 + wv * 16;

    int srcn = min(n0 + (lane & 15), N_NODES - 1);
    bf16x8 a = *(const bf16x8*)(xb + (size_t)srcn * IN_DIM + (lane >> 4) * 8);

    f32x4 z = {0.f, 0.f, 0.f, 0.f};
    f32x4 cR0 = z, cR1 = z, cR2 = z, cR3 = z;
    f32x4 c00 = z, c01 = z, c02 = z, c03 = z;
    f32x4 c10 = z, c11 = z, c12 = z, c13 = z;

#define B1FRAG(mat, jt) (*(const bf16x8*)(wb1 + ((mat) * 4 + (jt)) * 512 + lane * 8))
    cR0 = MFMA16x32(a, B1FRAG(0, 0), cR0, 0, 0, 0);
    cR1 = MFMA16x32(a, B1FRAG(0, 1), cR1, 0, 0, 0);
    cR2 = MFMA16x32(a, B1FRAG(0, 2), cR2, 0, 0, 0);
    cR3 = MFMA16x32(a, B1FRAG(0, 3), cR3, 0, 0, 0);
    c00 = MFMA16x32(a, B1FRAG(1, 0), c00, 0, 0, 0);
    c01 = MFMA16x32(a, B1FRAG(1, 1), c01, 0, 0, 0);
    c02 = MFMA16x32(a, B1FRAG(1, 2), c02, 0, 0, 0);
    c03 = MFMA16x32(a, B1FRAG(1, 3), c03, 0, 0, 0);
    c10 = MFMA16x32(a, B1FRAG(2, 0), c10, 0, 0, 0);
    c11 = MFMA16x32(a, B1FRAG(2, 1), c11, 0, 0, 0);
    c12 = MFMA16x32(a, B1FRAG(2, 2), c12, 0, 0, 0);
    c13 = MFMA16x32(a, B1FRAG(2, 3), c13, 0, 0, 0);
#undef B1FRAG

    if (n0 >= N_NODES) return;   // N%16==0 -> whole wave valid or invalid
    unsigned short* Y0 = Y;
    unsigned short* Y1 = Y + (size_t)N_NODES * HID_DIM;
    int col   = lane & 15;
    int rbase = n0 + (lane >> 4) * 4;

#define OUT1(cR, cA, cB, jt)                                          \
    {                                                                 \
        int j = (jt) * 16 + col;                                      \
        float bj = b1[j];                                             \
        _Pragma("unroll")                                             \
        for (int r = 0; r < 4; ++r) {                                 \
            size_t node = (size_t)(rbase + r);                        \
            Rb[node * HID_DIM + j] = f2bf(cR[r] + bj);                \
            Y0[node * HID_DIM + j] = f2bf(cA[r]);                     \
            Y1[node * HID_DIM + j] = f2bf(cB[r]);                     \
        }                                                             \
    }
    OUT1(cR0, c00, c10, 0)
    OUT1(cR1, c01, c11, 1)
    OUT1(cR2, c02, c12, 2)
    OUT1(cR3, c03, c13, 3)
#undef OUT1
}

__global__ __launch_bounds__(512, 8) void k_mgemm2(
    const unsigned short* __restrict__ h1b,  // [N][64] bf16
    const unsigned short* __restrict__ wb2,  // 24 B-frags
    const float* __restrict__ b2,
    unsigned short* __restrict__ Rb,         // [N][64] bf16: h1@root2 + b2
    unsigned short* __restrict__ Y)          // [2][N][64] bf16
{
    int tid = threadIdx.x;
    int lane = tid & 63;
    int wv   = tid >> 6;
    int n0   = blockIdx.x * 128 + wv * 16;

    int srcn = min(n0 + (lane & 15), N_NODES - 1);
    const unsigned short* pa = h1b + (size_t)srcn * HID_DIM + (lane >> 4) * 8;
    bf16x8 a0 = *(const bf16x8*)(pa);        // k 0..31
    bf16x8 a1 = *(const bf16x8*)(pa + 32);   // k 32..63

    f32x4 z = {0.f, 0.f, 0.f, 0.f};
    f32x4 cR0 = z, cR1 = z, cR2 = z, cR3 = z;
    f32x4 c00 = z, c01 = z, c02 = z, c03 = z;
    f32x4 c10 = z, c11 = z, c12 = z, c13 = z;

#define B2FRAG(mat, ks, jt) \
    (*(const bf16x8*)(wb2 + (((mat) * 2 + (ks)) * 4 + (jt)) * 512 + lane * 8))
#define DO2(cv, mat, jt)                                     \
    cv = MFMA16x32(a0, B2FRAG(mat, 0, jt), cv, 0, 0, 0);     \
    cv = MFMA16x32(a1, B2FRAG(mat, 1, jt), cv, 0, 0, 0);
    DO2(cR0, 0, 0) DO2(cR1, 0, 1) DO2(cR2, 0, 2) DO2(cR3, 0, 3)
    DO2(c00, 1, 0) DO2(c01, 1, 1) DO2(c02, 1, 2) DO2(c03, 1, 3)
    DO2(c10, 2, 0) DO2(c11, 2, 1) DO2(c12, 2, 2) DO2(c13, 2, 3)
#undef DO2
#undef B2FRAG

    if (n0 >= N_NODES) return;
    unsigned short* Y0 = Y;
    unsigned short* Y1 = Y + (size_t)N_NODES * HID_DIM;
    int col   = lane & 15;
    int rbase = n0 + (lane >> 4) * 4;

#define OUT2(cR, cA, cB, jt)                                          \
    {                                                                 \
        int j = (jt) * 16 + col;                                      \
        float bj = b2[j];                                             \
        _Pragma("unroll")                                             \
        for (int r = 0; r < 4; ++r) {                                 \
            size_t node = (size_t)(rbase + r);                        \
            Rb[node * HID_DIM + j] = f2bf(cR[r] + bj);                \
            Y0[node * HID_DIM + j] = f2bf(cA[r]);                     \
            Y1[node * HID_DIM + j] = f2bf(cB[r]);                     \
        }                                                             \
    }
    OUT2(cR0, c00, c10, 0)
    OUT2(cR1, c01, c11, 1)
    OUT2(cR2, c02, c12, 2)
    OUT2(cR3, c03, c13, 3)
#undef OUT2
}

// ============ gather-sum kernels (r17 structure, Rb bf16) ============

__global__ __launch_bounds__(512, 8) void k_gather1(
    const unsigned short* __restrict__ Y,   // [2][N][64] bf16
    const unsigned short* __restrict__ Rb,  // [N][64] bf16 (incl. b1)
    const int2* __restrict__ od,
    const int* __restrict__ elist,
    unsigned short* __restrict__ h1b)       // [N][64] bf16
{
    int tid = threadIdx.x;
    int lane = tid & 63;
    int wv   = __builtin_amdgcn_readfirstlane(tid >> 6);
    int n0   = __builtin_amdgcn_readfirstlane(blockIdx.x * 32 + wv * 4);

    int sub  = lane >> 4;
    int node = n0 + sub;
    int q    = lane & 15;
    int base = lane & 48;

    const unsigned short* Y0 = Y;
    const unsigned short* Y1 = Y + (size_t)N_NODES * HID_DIM;

    int2 o0 = od[node];
    int2 o1 = od[N_NODES + node];
    int d0 = o0.y, d1 = o1.y;
    int er0 = (q < d0) ? elist[o0.x + q] : 0;
    int er1 = (q < d1) ? elist[o1.x + q] : 0;

    int dm = max(d0, d1);
    dm = max(dm, __shfl_xor(dm, 16));
    dm = max(dm, __shfl_xor(dm, 32));
    int kend = min(dm, 16);

    float4 A0 = make_float4(0.f, 0.f, 0.f, 0.f);
    float4 A1 = make_float4(0.f, 0.f, 0.f, 0.f);
    for (int k = 0; k < kend; ++k) {
        int i0 = __shfl(er0, base + k);
        int i1 = __shfl(er1, base + k);
        uint2 u0 = *(const uint2*)(Y0 + (size_t)i0 * HID_DIM + q * 4);
        uint2 u1 = *(const uint2*)(Y1 + (size_t)i1 * HID_DIM + q * 4);
        float m0 = (k < d0) ? 1.0f : 0.0f;
        float m1 = (k < d1) ? 1.0f : 0.0f;
        BMACC4(A0, u0, m0)
        BMACC4(A1, u1, m1)
    }
    if (dm > 16) {
        for (int k = 16; k < dm; ++k) {
            int i0 = 0, i1 = 0;
            if (k < d0) i0 = elist[o0.x + k];
            if (k < d1) i1 = elist[o1.x + k];
            uint2 u0 = *(const uint2*)(Y0 + (size_t)i0 * HID_DIM + q * 4);
            uint2 u1 = *(const uint2*)(Y1 + (size_t)i1 * HID_DIM + q * 4);
            float m0 = (k < d0) ? 1.0f : 0.0f;
            float m1 = (k < d1) ? 1.0f : 0.0f;
            BMACC4(A0, u0, m0)
            BMACC4(A1, u1, m1)
        }
    }
    float i0v = 1.0f / fmaxf((float)d0, 1.0f);
    float i1v = 1.0f / fmaxf((float)d1, 1.0f);
    uint2 ru = *(const uint2*)(Rb + (size_t)node * HID_DIM + q * 4);
    float4 Rq; BUNPACK(Rq, ru)
    ushort4 o;
    o.x = f2bf(fmaxf(Rq.x + A0.x * i0v + A1.x * i1v, 0.0f));
    o.y = f2bf(fmaxf(Rq.y + A0.y * i0v + A1.y * i1v, 0.0f));
    o.z = f2bf(fmaxf(Rq.z + A0.z * i0v + A1.z * i1v, 0.0f));
    o.w = f2bf(fmaxf(Rq.w + A0.w * i0v + A1.w * i1v, 0.0f));
    *(ushort4*)(h1b + (size_t)node * HID_DIM + q * 4) = o;
}

__global__ __launch_bounds__(512, 8) void k_gather2(
    const unsigned short* __restrict__ Y,   // [2][N][64] bf16
    const unsigned short* __restrict__ Rb,  // [N][64] bf16 (incl. b2)
    const int2* __restrict__ od,
    const int* __restrict__ elist,
    const float* __restrict__ Wc,           // [64][2]
    const float* __restrict__ bc,           // [2]
    float* __restrict__ out)                // [N][2]
{
    int tid = threadIdx.x;
    int lane = tid & 63;
    int wv   = __builtin_amdgcn_readfirstlane(tid >> 6);
    int n0   = __builtin_amdgcn_readfirstlane(blockIdx.x * 32 + wv * 4);

    int sub  = lane >> 4;
    int node = n0 + sub;
    int q    = lane & 15;
    int base = lane & 48;

    const unsigned short* Y0 = Y;
    const unsigned short* Y1 = Y + (size_t)N_NODES * HID_DIM;

    int2 o0 = od[node];
    int2 o1 = od[N_NODES + node];
    int d0 = o0.y, d1 = o1.y;
    int er0 = (q < d0) ? elist[o0.x + q] : 0;
    int er1 = (q < d1) ? elist[o1.x + q] : 0;

    int dm = max(d0, d1);
    dm = max(dm, __shfl_xor(dm, 16));
    dm = max(dm, __shfl_xor(dm, 32));
    int kend = min(dm, 16);

    float4 A0 = make_float4(0.f, 0.f, 0.f, 0.f);
    float4 A1 = make_float4(0.f, 0.f, 0.f, 0.f);
    for (int k = 0; k < kend; ++k) {
        int i0 = __shfl(er0, base + k);
        int i1 = __shfl(er1, base + k);
        uint2 u0 = *(const uint2*)(Y0 + (size_t)i0 * HID_DIM + q * 4);
        uint2 u1 = *(const uint2*)(Y1 + (size_t)i1 * HID_DIM + q * 4);
        float m0 = (k < d0) ? 1.0f : 0.0f;
        float m1 = (k < d1) ? 1.0f : 0.0f;
        BMACC4(A0, u0, m0)
        BMACC4(A1, u1, m1)
    }
    if (dm > 16) {
        for (int k = 16; k < dm; ++k) {
            int i0 = 0, i1 = 0;
            if (k < d0) i0 = elist[o0.x + k];
            if (k < d1) i1 = elist[o1.x + k];
            uint2 u0 = *(const uint2*)(Y0 + (size_t)i0 * HID_DIM + q * 4);
            uint2 u1 = *(const uint2*)(Y1 + (size_t)i1 * HID_DIM + q * 4);
            float m0 = (k < d0) ? 1.0f : 0.0f;
            float m1 = (k < d1) ? 1.0f : 0.0f;
            BMACC4(A0, u0, m0)
            BMACC4(A1, u1, m1)
        }
    }
    float i0v = 1.0f / fmaxf((float)d0, 1.0f);
    float i1v = 1.0f / fmaxf((float)d1, 1.0f);
    uint2 ru = *(const uint2*)(Rb + (size_t)node * HID_DIM + q * 4);
    float4 Rq; BUNPACK(Rq, ru)
    float4 h2;
    h2.x = fmaxf(Rq.x + A0.x * i0v + A1.x * i1v, 0.0f);
    h2.y = fmaxf(Rq.y + A0.y * i0v + A1.y * i1v, 0.0f);
    h2.z = fmaxf(Rq.z + A0.z * i0v + A1.z * i1v, 0.0f);
    h2.w = fmaxf(Rq.w + A0.w * i0v + A1.w * i1v, 0.0f);

    float4 wcA = *(const float4*)(Wc + 8 * q);
    float4 wcB = *(const float4*)(Wc + 8 * q + 4);
    float v0 = h2.x * wcA.x + h2.y * wcA.z + h2.z * wcB.x + h2.w * wcB.z;
    float v1 = h2.x * wcA.y + h2.y * wcA.w + h2.z * wcB.y + h2.w * wcB.w;
#pragma unroll
    for (int off = 1; off <= 8; off <<= 1) {
        v0 += __shfl_xor(v0, off);
        v1 += __shfl_xor(v1, off);
    }
    if (q == 0) {
        out[(size_t)node * 2 + 0] = v0 + bc[0];
        out[(size_t)node * 2 + 1] = v1 + bc[1];
    }
}

// ============ launch ============

extern "C" void kernel_launch(void* const* d_in, const int* in_sizes, int n_in,
                              void* d_out, int out_size, void* d_ws, size_t ws_size,
                              hipStream_t stream) {
    const float* x     = (const float*)d_in[0];
    const int*   ei    = (const int*)d_in[1];
    const int*   ea    = (const int*)d_in[2];
    const float* W1    = (const float*)d_in[3];
    const float* root1 = (const float*)d_in[4];
    const float* b1    = (const float*)d_in[5];
    const float* W2    = (const float*)d_in[6];
    const float* root2 = (const float*)d_in[7];
    const float* b2    = (const float*)d_in[8];
    const float* Wc    = (const float*)d_in[9];
    const float* bc    = (const float*)d_in[10];
    float* out = (float*)d_out;

    // ws layout (bytes), peak ~69.6 MB (proven budget >= 77.6 MB):
    //   deg    @ 0        : 2N int   (800000)
    //   offs   @ 800000   : 2N int   (800000)
    //   od     @ 1600000  : 2N int2  (1600000)
    //   elist  @ 3200000  : E int    (4000000)
    //   cursor @ 7200000  : 2N int   (800000)
    //   bsum   @ 8000000  : 4096
    //   rd     @ 8004096  : E int    (4000000)
    //   Y      @ 12004096 : 2N*64 bf16 (25600000)
    //   Rb     @ 37604096 : N*64 bf16  (12800000)
    //   h1b    @ 50404096 : N*64 bf16  (12800000)
    //   xb     @ 63204096 : N*32 bf16  (6400000)
    //   wb1    @ 69604096 : 6144 bf16  (12288)
    //   wb2    @ 69616384 : 12288 bf16 (24576)
    char* ws = (char*)d_ws;
    int*   deg    = (int*)(ws);
    int*   offs   = (int*)(ws + 800000);
    int2*  od     = (int2*)(ws + 1600000);
    int*   elist  = (int*)(ws + 3200000);
    int*   cursor = (int*)(ws + 7200000);
    int*   bsum   = (int*)(ws + 8000000);
    int*   rd     = (int*)(ws + 8004096);
    unsigned short* Y   = (unsigned short*)(ws + 12004096);
    unsigned short* Rb  = (unsigned short*)(ws + 37604096);
    unsigned short* h1b = (unsigned short*)(ws + 50404096);
    unsigned short* xb  = (unsigned short*)(ws + 63204096);
    unsigned short* wb1 = (unsigned short*)(ws + 69604096);
    unsigned short* wb2 = (unsigned short*)(ws + 69616384);

    const int nblk_scan = (N2 + 255) / 256;                            // 782
    const int grid_e    = (N_EDGES + 255) / 256;                       // 3907
    const int grid_cf   = ((N_EDGES + ECHUNK - 1) / ECHUNK) * NRANGE;  // 489*8
    const int grid_m    = (N_NODES + 127) / 128;                       // 782 (mfma gemms)
    const int grid_n    = N_NODES / 32;                                // 3125 (gathers)

    k_prep<<<grid_e, 256, 0, stream>>>(ei, ea, x, root1, W1, root2, W2,
                                       rd, deg, xb, wb1, wb2);
    k_count<<<grid_cf, 256, 0, stream>>>(rd, deg);
    k_scan_local<<<nblk_scan, 256, 0, stream>>>(deg, offs, bsum);
    k_scan_blocks<<<1, 64, 0, stream>>>(bsum, nblk_scan);
    k_scan_add<<<nblk_scan, 256, 0, stream>>>(offs, bsum, deg, cursor, od);
    k_fill<<<grid_cf, 256, 0, stream>>>(rd, ei, cursor, elist);

    // layer 1: MFMA transform, then gather (linearity: mean(x)@W == mean(x@W))
    k_mgemm1<<<grid_m, 512, 0, stream>>>(xb, wb1, b1, Rb, Y);
    k_gather1<<<grid_n, 512, 0, stream>>>(Y, Rb, od, elist, h1b);

    // layer 2 + classifier
    k_mgemm2<<<grid_m, 512, 0, stream>>>(h1b, wb2, b2, Rb, Y);
    k_gather2<<<grid_n, 512, 0, stream>>>(Y, Rb, od, elist, Wc, bc, out);
}